// Round 1
// baseline (508.025 us; speedup 1.0000x reference)
//
#include <hip/hip_runtime.h>

// LePEAttention: B=16, H=W=64, C=384, HEADS=12, hd=32, IDX=0 (vertical strips)
// Pipeline: cvt(fp32->fp16) -> QKV GEMM (MFMA f16) -> lepe conv -> per-strip-head
// attention -> proj GEMM (+bias, fp32 out).
// All MFMA: v_mfma_f32_16x16x32_f16. Layouts per HW-verified guide:
//   A frag: A[m=lane&15][k=(lane>>4)*8+j] ; B frag mirrored ; C/D: col=lane&15, row=(lane>>4)*4+reg

typedef _Float16 f16;
typedef _Float16 f16x8 __attribute__((ext_vector_type(8)));
typedef float    f32x4 __attribute__((ext_vector_type(4)));

__device__ __forceinline__ f32x4 mfma_16x16x32(f16x8 a, f16x8 b, f32x4 c) {
  return __builtin_amdgcn_mfma_f32_16x16x32_f16(a, b, c, 0, 0, 0);
}

// ---------------- fp32 -> fp16 convert (8 elems/thread) ----------------
__global__ __launch_bounds__(256) void k_cvt(const float* __restrict__ src,
                                             f16* __restrict__ dst, int n8) {
  int i = blockIdx.x * 256 + threadIdx.x;
  if (i >= n8) return;
  const f32x4* s4 = (const f32x4*)src;
  f32x4 a = s4[2 * i], b = s4[2 * i + 1];
  f16x8 o;
#pragma unroll
  for (int j = 0; j < 4; ++j) { o[j] = (f16)a[j]; o[4 + j] = (f16)b[j]; }
  *(f16x8*)&dst[(long)i * 8] = o;
}

// ---------------- GEMM: C[M x NDIM] = A[M x 384] * Bt[NDIM x 384]^T ----------------
// 128x128 block tile, BK=64, 256 threads (4 waves in 2x2), 4x4 MFMA tiles per wave.
template <int NDIM, bool FINAL>
__global__ __launch_bounds__(256) void k_gemm(const f16* __restrict__ A,
                                              const f16* __restrict__ Bt,
                                              const float* __restrict__ bias,
                                              f16* __restrict__ Ch,
                                              float* __restrict__ Cf) {
  constexpr int KD = 384;
  constexpr int LDSP = 72;  // padded stride in halfs: 144B = 9*16B, 2-way bank alias only
  constexpr int NT = NDIM / 128;
  __shared__ f16 As[128 * LDSP];
  __shared__ f16 Bs[128 * LDSP];

  const int tid = threadIdx.x;
  const int lane = tid & 63;
  const int wave = tid >> 6;
  const int wr = wave >> 1, wc = wave & 1;
  const int ln = lane & 15, quad = lane >> 4;
  const int q8 = quad * 8;
  const int mt = blockIdx.x / NT;
  const int nt = blockIdx.x % NT;
  const long m0 = (long)mt * 128;
  const int n0 = nt * 128;

  f32x4 acc[4][4] = {};

  for (int k0 = 0; k0 < KD; k0 += 64) {
    // stage A,B tiles (128x64 f16 each): 4 rounds x 256 threads x 16B
#pragma unroll
    for (int r = 0; r < 4; ++r) {
      int flat = r * 256 + tid;
      int row = flat >> 3;
      int kk = (flat & 7) * 8;
      f16x8 av = *(const f16x8*)&A[(m0 + row) * KD + k0 + kk];
      *(f16x8*)&As[row * LDSP + kk] = av;
      f16x8 bv = *(const f16x8*)&Bt[(long)(n0 + row) * KD + k0 + kk];
      *(f16x8*)&Bs[row * LDSP + kk] = bv;
    }
    __syncthreads();
#pragma unroll
    for (int ks = 0; ks < 2; ++ks) {
      f16x8 a[4], b[4];
#pragma unroll
      for (int i = 0; i < 4; ++i)
        a[i] = *(const f16x8*)&As[(wr * 64 + i * 16 + ln) * LDSP + ks * 32 + q8];
#pragma unroll
      for (int j = 0; j < 4; ++j)
        b[j] = *(const f16x8*)&Bs[(wc * 64 + j * 16 + ln) * LDSP + ks * 32 + q8];
#pragma unroll
      for (int i = 0; i < 4; ++i)
#pragma unroll
        for (int j = 0; j < 4; ++j)
          acc[i][j] = mfma_16x16x32(a[i], b[j], acc[i][j]);
    }
    __syncthreads();
  }

#pragma unroll
  for (int i = 0; i < 4; ++i) {
#pragma unroll
    for (int j = 0; j < 4; ++j) {
      int gc = n0 + wc * 64 + j * 16 + ln;
#pragma unroll
      for (int r = 0; r < 4; ++r) {
        long gr = m0 + wr * 64 + i * 16 + quad * 4 + r;
        float v = acc[i][j][r];
        if (FINAL)
          Cf[gr * NDIM + gc] = v + bias[gc];
        else
          Ch[gr * (long)NDIM + gc] = (f16)v;
      }
    }
  }
}

// ---------------- LePE depthwise 3x3 conv -> afused (fp16) ----------------
// afused[b, h*64+w, c] = conv(x)[b,h,w,c] + lepe_b[c]
__global__ __launch_bounds__(256) void k_lepe(const f16* __restrict__ x16,
                                              const float* __restrict__ lw,
                                              const float* __restrict__ lb,
                                              f16* __restrict__ afused) {
  __shared__ float ws[384 * 9];
  __shared__ float bs[384];
  for (int i = threadIdx.x; i < 384 * 9; i += 256) ws[i] = lw[i];
  for (int i = threadIdx.x; i < 384; i += 256) bs[i] = lb[i];
  __syncthreads();

  int chunk = blockIdx.x * 256 + threadIdx.x;  // token * 48 + cgroup
  int token = chunk / 48;
  int c0 = (chunk % 48) * 8;
  int b = token >> 12, n = token & 4095;
  int h = n >> 6, w = n & 63;

  float acc[8];
#pragma unroll
  for (int cc = 0; cc < 8; ++cc) acc[cc] = bs[c0 + cc];
#pragma unroll
  for (int ky = 0; ky < 3; ++ky) {
    int hh = h + ky - 1;
    if (hh < 0 || hh > 63) continue;
#pragma unroll
    for (int kx = 0; kx < 3; ++kx) {
      int ww = w + kx - 1;
      if (ww < 0 || ww > 63) continue;
      f16x8 xv = *(const f16x8*)&x16[((long)((b << 12) + (hh << 6) + ww)) * 384 + c0];
#pragma unroll
      for (int cc = 0; cc < 8; ++cc)
        acc[cc] += (float)xv[cc] * ws[(c0 + cc) * 9 + ky * 3 + kx];
    }
  }
  f16x8 o;
#pragma unroll
  for (int cc = 0; cc < 8; ++cc) o[cc] = (f16)acc[cc];
  *(f16x8*)&afused[(long)token * 384 + c0] = o;
}

// ---------------- attention: one wave per (strip, head) ----------------
// strip s=(b,w): tokens n = l*64+w, l=0..63. Out written at n_out = w*64+l (torch quirk),
// accumulated into afused (which holds lepe).
__global__ __launch_bounds__(64) void k_attn(const f16* __restrict__ qkv,
                                             f16* __restrict__ afused) {
  __shared__ f16 vt[32 * 72];        // v^T: [d][l], stride 72
  __shared__ f16 qkbuf[2 * 64 * 56]; // qs, ks: [l][d] stride 56; ps overlays after use
  f16* qs = qkbuf;
  f16* ks = qkbuf + 64 * 56;
  f16* ps = qkbuf;                   // [l][m] stride 72, 64*72=4608 <= 7168

  const int lane = threadIdx.x;
  const int hh = blockIdx.x % 12;
  const int s = blockIdx.x / 12;
  const int b = s >> 6, w = s & 63;
  const int ln = lane & 15, quad = lane >> 4;
  const int q8 = quad * 8;
  const long baseTok = ((long)b << 12) + w;

  // load q,k,v for this head: 64 tokens x 32 halfs each
#pragma unroll
  for (int r = 0; r < 4; ++r) {
    int flat = r * 64 + lane;
    int l = flat >> 2;
    int dg = (flat & 3) * 8;
    long ta = (baseTok + (long)l * 64) * 1152 + hh * 32 + dg;
    f16x8 qv = *(const f16x8*)&qkv[ta];
    f16x8 kv = *(const f16x8*)&qkv[ta + 384];
    f16x8 vv = *(const f16x8*)&qkv[ta + 768];
    *(f16x8*)&qs[l * 56 + dg] = qv;
    *(f16x8*)&ks[l * 56 + dg] = kv;
#pragma unroll
    for (int ii = 0; ii < 8; ++ii) vt[(dg + ii) * 72 + l] = vv[ii];
  }
  __syncthreads();

  // S = q @ k^T  (64x64, K=32 -> one mfma step)
  f16x8 aq[4], bk[4];
#pragma unroll
  for (int i = 0; i < 4; ++i) aq[i] = *(const f16x8*)&qs[(i * 16 + ln) * 56 + q8];
#pragma unroll
  for (int j = 0; j < 4; ++j) bk[j] = *(const f16x8*)&ks[(j * 16 + ln) * 56 + q8];
  f32x4 sc[4][4] = {};
#pragma unroll
  for (int i = 0; i < 4; ++i)
#pragma unroll
    for (int j = 0; j < 4; ++j) sc[i][j] = mfma_16x16x32(aq[i], bk[j], sc[i][j]);
  __syncthreads();  // q/k reads done; ps may overwrite

  // softmax over rows (deferred normalization)
  const float scale = 0.17677669529663687f;  // 32^-0.5
  float rs[4][4];
#pragma unroll
  for (int i = 0; i < 4; ++i) {
#pragma unroll
    for (int r = 0; r < 4; ++r) {
      float m = -1e30f;
#pragma unroll
      for (int j = 0; j < 4; ++j) m = fmaxf(m, sc[i][j][r]);
#pragma unroll
      for (int off = 1; off < 16; off <<= 1) m = fmaxf(m, __shfl_xor(m, off, 64));
      m *= scale;
      float sum = 0.f;
#pragma unroll
      for (int j = 0; j < 4; ++j) {
        float p = __expf(sc[i][j][r] * scale - m);
        sc[i][j][r] = p;
        sum += p;
      }
#pragma unroll
      for (int off = 1; off < 16; off <<= 1) sum += __shfl_xor(sum, off, 64);
      rs[i][r] = 1.0f / sum;
    }
  }

  // P -> LDS (C/D layout -> A-operand layout round trip)
#pragma unroll
  for (int i = 0; i < 4; ++i)
#pragma unroll
    for (int j = 0; j < 4; ++j)
#pragma unroll
      for (int r = 0; r < 4; ++r)
        ps[(i * 16 + quad * 4 + r) * 72 + j * 16 + ln] = (f16)sc[i][j][r];
  __syncthreads();

  // O = P @ V  (64x32, K=64 -> 2 mfma steps)
  f32x4 oc[4][2] = {};
#pragma unroll
  for (int ks2 = 0; ks2 < 2; ++ks2) {
    f16x8 ap[4], bv[2];
#pragma unroll
    for (int i = 0; i < 4; ++i)
      ap[i] = *(const f16x8*)&ps[(i * 16 + ln) * 72 + ks2 * 32 + q8];
#pragma unroll
    for (int j = 0; j < 2; ++j)
      bv[j] = *(const f16x8*)&vt[(j * 16 + ln) * 72 + ks2 * 32 + q8];
#pragma unroll
    for (int i = 0; i < 4; ++i)
#pragma unroll
      for (int j = 0; j < 2; ++j) oc[i][j] = mfma_16x16x32(ap[i], bv[j], oc[i][j]);
  }

  // epilogue: normalize, add into afused at transposed flat index n_out = w*64 + l
#pragma unroll
  for (int i = 0; i < 4; ++i)
#pragma unroll
    for (int j = 0; j < 2; ++j)
#pragma unroll
      for (int r = 0; r < 4; ++r) {
        int l = i * 16 + quad * 4 + r;
        int d = j * 16 + ln;
        long g = ((long)b * 4096 + w * 64 + l) * 384 + hh * 32 + d;
        float v = oc[i][j][r] * rs[i][r];
        afused[g] = (f16)(v + (float)afused[g]);
      }
}

// ---------------- launch ----------------
extern "C" void kernel_launch(void* const* d_in, const int* in_sizes, int n_in,
                              void* d_out, int out_size, void* d_ws, size_t ws_size,
                              hipStream_t stream) {
  const float* x      = (const float*)d_in[0];
  const float* qkv_w  = (const float*)d_in[1];
  const float* proj_w = (const float*)d_in[2];
  const float* proj_b = (const float*)d_in[3];
  const float* lepe_w = (const float*)d_in[4];
  const float* lepe_b = (const float*)d_in[5];
  float* out = (float*)d_out;

  char* ws = (char*)d_ws;
  f16* x16    = (f16*)(ws + 0);          //  50,331,648 B
  f16* w16    = (f16*)(ws + 50331648);   //     884,736 B
  f16* pw16   = (f16*)(ws + 51216384);   //     294,912 B
  f16* qkv16  = (f16*)(ws + 51511296);   // 150,994,944 B
  f16* afused = (f16*)(ws + 202506240);  //  50,331,648 B  (total ~241 MB)

  k_cvt<<<12288, 256, 0, stream>>>(x, x16, 3145728);
  k_cvt<<<216, 256, 0, stream>>>(qkv_w, w16, 55296);
  k_cvt<<<72, 256, 0, stream>>>(proj_w, pw16, 18432);
  // QKV: [65536 x 384] @ [1152 x 384]^T -> qkv16
  k_gemm<1152, false><<<512 * 9, 256, 0, stream>>>(x16, w16, nullptr, qkv16, nullptr);
  // lepe conv -> afused
  k_lepe<<<12288, 256, 0, stream>>>(x16, lepe_w, lepe_b, afused);
  // attention += into afused
  k_attn<<<1024 * 12, 64, 0, stream>>>(qkv16, afused);
  // proj: [65536 x 384] @ [384 x 384]^T + bias -> out (fp32)
  k_gemm<384, true><<<512 * 3, 256, 0, stream>>>(afused, pw16, proj_b, nullptr, out);
}